// Round 4
// baseline (180.349 us; speedup 1.0000x reference)
//
#include <hip/hip_runtime.h>
#include <stdint.h>

// AWQGemm: x[1024,4096] f32, qweight[4096,1376] i32, scales[32,11008] f32,
// qzeros[32,1376] i32 -> C[1024,11008] f32
#define M_DIM 1024
#define K_DIM 4096
#define N_DIM 11008
#define NC_DIM 1376
#define G_DIM 32
#define GS 128

typedef __bf16 bf16x8 __attribute__((ext_vector_type(8)));
typedef float f32x4 __attribute__((ext_vector_type(4)));
typedef float f32x2 __attribute__((ext_vector_type(2)));
typedef unsigned short ushort8 __attribute__((ext_vector_type(8)));

typedef __attribute__((address_space(1))) char as1_char;
typedef __attribute__((address_space(3))) char as3_char;
#define GLDS16(g, l) __builtin_amdgcn_global_load_lds((as1_char*)(g), (as3_char*)(l), 16, 0, 0)

static __device__ __forceinline__ int awq_shift(int j) {
  return ((j & 1) << 4) | ((j >> 1) << 2);
}

// fp32 -> bf16 bits, RNE
static __device__ __forceinline__ unsigned short f2bf(float f) {
  union { float f; uint32_t u; } c; c.f = f;
  uint32_t u = c.u;
  return (unsigned short)((u + 0x7FFFu + ((u >> 16) & 1u)) >> 16);
}

// ---------------- Stage 0a: x fp32 -> bf16 ----------------
__global__ void k_cvt_x(const float* __restrict__ x, unsigned short* __restrict__ xb) {
  int i = blockIdx.x * blockDim.x + threadIdx.x;
  int base = i * 8;
  float4 v0 = *(const float4*)(x + base);
  float4 v1 = *(const float4*)(x + base + 4);
  ushort8 o;
  o[0] = f2bf(v0.x); o[1] = f2bf(v0.y); o[2] = f2bf(v0.z); o[3] = f2bf(v0.w);
  o[4] = f2bf(v1.x); o[5] = f2bf(v1.y); o[6] = f2bf(v1.z); o[7] = f2bf(v1.w);
  *(ushort8*)(xb + base) = o;
}

// ---------------- Stage 0b: nibble transpose ----------------
// Wq[wr][n], wr=k/8: bits 4j of word = nibble of k=wr*8+j (PLAIN j order).
// One word = one MFMA B-fragment's 8 k-values for column n.
__global__ void k_wqt(const int* __restrict__ qw, int* __restrict__ Wq) {
  int t = blockIdx.x * 256 + threadIdx.x;   // 512*1376 threads
  int wr = t / NC_DIM, c = t % NC_DIM;
  int in[8];
#pragma unroll
  for (int j = 0; j < 8; ++j) in[j] = qw[(size_t)(wr * 8 + j) * NC_DIM + c];
  int out[8];
#pragma unroll
  for (int j2 = 0; j2 < 8; ++j2) {
    int sh = awq_shift(j2);
    int o = 0;
#pragma unroll
    for (int j = 0; j < 8; ++j) o |= ((in[j] >> sh) & 0xF) << (4 * j);
    out[j2] = o;
  }
  int4* dst = (int4*)(Wq + (size_t)wr * N_DIM + c * 8);
  dst[0] = make_int4(out[0], out[1], out[2], out[3]);
  dst[1] = make_int4(out[4], out[5], out[6], out[7]);
}

// ---------------- Stage 0c: per-(g,n) {scale, zero*scale} table ----------------
__global__ void k_tab(const int* __restrict__ qz, const float* __restrict__ scales,
                      float* __restrict__ SZ) {
  int t = blockIdx.x * 256 + threadIdx.x;   // 32*11008 threads; t = g*N + n
  int g = t / N_DIM, n = t % N_DIM;
  float s = scales[t];
  int z = (qz[(size_t)g * NC_DIM + (n >> 3)] >> awq_shift(n & 7)) & 0xF;
  f32x2 v; v[0] = s; v[1] = (float)z * s;
  *(f32x2*)(SZ + (size_t)t * 2) = v;
}

// ---------------- Stage 1: 256x256 8-phase GEMM, in-register B dequant -------
// R2 schedule skeleton (verified race-free, 0 bank conflicts). B-path changed:
// stage 8KB of Wq words per K-tile (1 gload_lds), dequant in-register.
// LDS: A 2buf x 2reg x 16KB = 64KB @0; Bw single-buf [8 rows][258 dw] @65536.
// Per tile stages: p0: A1(t+1)[2]; p1: Bw(t+1)[1] (+4 sz loads, t odd);
// p3: A0(t+2)[2]; vmcnt(2) leaves only A0(t+2). Bw single-buffer is safe:
// last read p0(t), overwrite issued p1(t) after two barriers.
#define NT (K_DIM / 64)
#define REG_BYTES 16384
#define BW_OFF 65536

#define RD(base, off) (*(const bf16x8*)((const unsigned char*)(base) + (off)))
#define MFMA16(a, b, c) __builtin_amdgcn_mfma_f32_16x16x32_bf16((a), (b), (c), 0, 0, 0)
#define SBAR0() __builtin_amdgcn_sched_barrier(0)

__launch_bounds__(512, 2)
__global__ void k_gemm8(const unsigned short* __restrict__ A,
                        const int* __restrict__ Wq,
                        const float* __restrict__ SZ,
                        float* __restrict__ C) {
  __shared__ __attribute__((aligned(16))) unsigned char LDS[73792];

  const int tid = threadIdx.x;
  const int lane = tid & 63;
  const int w = tid >> 6;       // 0..7
  const int wm = w >> 2;        // 0..1  M half
  const int wn = w & 3;         // 0..3  N quarter
  const int u = lane & 15;
  const int h4 = lane >> 4;     // 0..3  k-slot
  const int xor16 = (lane & 7) << 4;
  const int kpos0 = (h4 * 16) ^ xor16;
  const int kpos1 = (64 + h4 * 16) ^ xor16;
  const int aoff = u * 128;

  // bijective XCD swizzle: nwg=172 = 8*21+4; M fastest so 4 row-tiles share B panel
  const int orig = blockIdx.x;
  const int xcd = orig & 7, loc = orig >> 3;
  const int qq = 21, rr = 4;
  const int swz = (xcd < rr) ? xcd * (qq + 1) + loc : rr * (qq + 1) + (xcd - rr) * qq + loc;
  const int m0 = (swz & 3) * 256;
  const int nb0 = (swz >> 2) * 256;

  // A staging addresses (R2 semantics: pre-swizzled source, linear LDS dest)
  const int kb_src = (((lane & 7) ^ ((lane >> 3) & 7)) << 4) >> 1;
  const int srow = w * 16 + (lane >> 3);
  const unsigned short* gA0 = A + (size_t)(m0 + srow) * K_DIM + kb_src;
  const unsigned short* gA1 = gA0 + (size_t)128 * K_DIM;
  const int ldsw = w * 2048;

#define STAGE_A(gp, T, bufoff, region)                                            \
  do {                                                                            \
    const unsigned short* _g = (gp) + (size_t)(T) * 64;                           \
    unsigned char* _l = LDS + (bufoff) + (region) * REG_BYTES + ldsw;             \
    GLDS16(_g, _l);                                                               \
    GLDS16(_g + (size_t)8 * K_DIM, _l + 1024);                                    \
  } while (0)

  // Bw staging: wave w stages word-row (t*8+w); lanes fill 1024B linearly.
  const int* gBw = Wq + (size_t)w * N_DIM + nb0 + lane * 4;
#define STAGE_BW(T) GLDS16(gBw + (size_t)(T) * 8 * N_DIM, LDS + BW_OFF + w * 1032)

  // per-lane n for each nf, and SZ pointers
  const int n_base = nb0 + wn * 64 + u;
  // Bw LDS read base: row = ks*4 + h4, col dword = wn*64 + nf*16 + u
  const unsigned char* rdBw = LDS + BW_OFF + h4 * 1032 + (wn * 64 + u) * 4;

  f32x4 acc[8][4] = {};
  f32x2 sz[4];

  // ---- prologue ----
  STAGE_A(gA0, 0, 0, 0);
  STAGE_A(gA1, 0, 0, 1);
  STAGE_BW(0);
  SBAR0();
#pragma unroll
  for (int nf = 0; nf < 4; ++nf)
    sz[nf] = *(const f32x2*)(SZ + ((size_t)0 * N_DIM + n_base + nf * 16) * 2);
  SBAR0();
  STAGE_A(gA0, 1, 65536 - 65536 + 65536, 0);  // buf1 region A0
  asm volatile("s_waitcnt vmcnt(2)" ::: "memory");
  __builtin_amdgcn_s_barrier();

#pragma unroll 2
  for (int t = 0; t < NT; ++t) {
    const int cur = t & 1;
    const int bo_c = cur * 32768;          // A buffers: 2 x 32KB
    const int bo_n = (cur ^ 1) * 32768;
    const unsigned char* rdA = LDS + bo_c + wm * REG_BYTES;

    bf16x8 aR[4][2], bF[4][2];
    int wrd[4][2];

    // ---------- phase 0: read Bw words + A(rb0-3 lo-half); stage A1(t+1); unpack bLo
#pragma unroll
    for (int nf = 0; nf < 4; ++nf)
#pragma unroll
      for (int ks = 0; ks < 2; ++ks)
        wrd[nf][ks] = *(const int*)(rdBw + ks * 4128 + nf * 64);
#pragma unroll
    for (int mi = 0; mi < 4; ++mi) {
      aR[mi][0] = RD(rdA, mi * 2048 + aoff + kpos0);
      aR[mi][1] = RD(rdA, mi * 2048 + aoff + kpos1);
    }
    if (t + 1 < NT) STAGE_A(gA1, t + 1, bo_n, 1);
#pragma unroll
    for (int nf = 0; nf < 2; ++nf)
#pragma unroll
      for (int ks = 0; ks < 2; ++ks) {
        int wv = wrd[nf][ks];
        float s = sz[nf][0], zz = sz[nf][1];
        bf16x8 f;
#pragma unroll
        for (int j = 0; j < 8; ++j)
          f[j] = (__bf16)fmaf((float)((wv >> (4 * j)) & 0xF), s, -zz);
        bF[nf][ks] = f;
      }
    __builtin_amdgcn_s_barrier();
    __builtin_amdgcn_s_setprio(1);
#pragma unroll
    for (int mi = 0; mi < 4; ++mi)
#pragma unroll
      for (int nf = 0; nf < 2; ++nf) {
        acc[mi][nf] = MFMA16(aR[mi][0], bF[nf][0], acc[mi][nf]);
        acc[mi][nf] = MFMA16(aR[mi][1], bF[nf][1], acc[mi][nf]);
      }
    __builtin_amdgcn_s_setprio(0);
    __builtin_amdgcn_s_barrier();

    // ---------- phase 1: stage Bw(t+1); sz loads (t odd); unpack bHi
    if (t + 1 < NT) STAGE_BW(t + 1);
    SBAR0();
    if ((t & 1) && (t + 1 < NT)) {
      const int gg = (t + 1) >> 1;
#pragma unroll
      for (int nf = 0; nf < 4; ++nf)
        sz[nf] = *(const f32x2*)(SZ + ((size_t)gg * N_DIM + n_base + nf * 16) * 2);
    }
    SBAR0();
#pragma unroll
    for (int nf = 2; nf < 4; ++nf)
#pragma unroll
      for (int ks = 0; ks < 2; ++ks) {
        int wv = wrd[nf][ks];
        float s = sz[nf][0], zz = sz[nf][1];   // note: t even keeps same group; t odd: bHi
        bf16x8 f;                              // uses OLD sz? -> see below
#pragma unroll
        for (int j = 0; j < 8; ++j)
          f[j] = (__bf16)fmaf((float)((wv >> (4 * j)) & 0xF), s, -zz);
        bF[nf][ks] = f;
      }
    __builtin_amdgcn_s_barrier();
    __builtin_amdgcn_s_setprio(1);
#pragma unroll
    for (int mi = 0; mi < 4; ++mi)
#pragma unroll
      for (int nf = 0; nf < 2; ++nf) {
        acc[mi][nf + 2] = MFMA16(aR[mi][0], bF[nf + 2][0], acc[mi][nf + 2]);
        acc[mi][nf + 2] = MFMA16(aR[mi][1], bF[nf + 2][1], acc[mi][nf + 2]);
      }
    __builtin_amdgcn_s_setprio(0);
    __builtin_amdgcn_s_barrier();

    // ---------- phase 2: read A hi-half
#pragma unroll
    for (int mi = 0; mi < 4; ++mi) {
      aR[mi][0] = RD(rdA, (mi + 4) * 2048 + aoff + kpos0);
      aR[mi][1] = RD(rdA, (mi + 4) * 2048 + aoff + kpos1);
    }
    __builtin_amdgcn_s_barrier();
    __builtin_amdgcn_s_setprio(1);
#pragma unroll
    for (int mi = 0; mi < 4; ++mi)
#pragma unroll
      for (int nf = 0; nf < 2; ++nf) {
        acc[mi + 4][nf + 2] = MFMA16(aR[mi][0], bF[nf + 2][0], acc[mi + 4][nf + 2]);
        acc[mi + 4][nf + 2] = MFMA16(aR[mi][1], bF[nf + 2][1], acc[mi + 4][nf + 2]);
      }
    __builtin_amdgcn_s_setprio(0);
    __builtin_amdgcn_s_barrier();

    // ---------- phase 3: stage A0(t+2); counted vmcnt
    if (t + 2 < NT) STAGE_A(gA0, t + 2, bo_c, 0);
    __builtin_amdgcn_s_barrier();
    __builtin_amdgcn_s_setprio(1);
#pragma unroll
    for (int mi = 0; mi < 4; ++mi)
#pragma unroll
      for (int nf = 0; nf < 2; ++nf) {
        acc[mi + 4][nf] = MFMA16(aR[mi][0], bF[nf][0], acc[mi + 4][nf]);
        acc[mi + 4][nf] = MFMA16(aR[mi][1], bF[nf][1], acc[mi + 4][nf]);
      }
    __builtin_amdgcn_s_setprio(0);
    if (t < NT - 2) {
      asm volatile("s_waitcnt vmcnt(2)" ::: "memory");
    } else {
      asm volatile("s_waitcnt vmcnt(0)" ::: "memory");
    }
    __builtin_amdgcn_s_barrier();
  }

  // ---- epilogue: C/D map col=lane&15, row=(lane>>4)*4+r [m89]
  const int crow0 = m0 + wm * 128 + h4 * 4;
  const int ccol0 = nb0 + wn * 64 + u;
#pragma unroll
  for (int mi = 0; mi < 8; ++mi)
#pragma unroll
    for (int nf = 0; nf < 4; ++nf)
#pragma unroll
      for (int r = 0; r < 4; ++r)
        C[(size_t)(crow0 + mi * 16 + r) * N_DIM + ccol0 + nf * 16] = acc[mi][nf][r];
}

// IMPORTANT correctness note on phase 1's sz usage: bHi unpack for tile t must
// use tile t's group g(t)=t>>1. The (t odd) reload targets g(t+1)=g(t)+... :
// g(t+1) for t odd = (t+1)/2 = g(t)+... t=1: g(1)=0, reload gg=1 BEFORE bHi
// unpack would be WRONG. The SBAR0 brackets order issue only; the compiler's
// register dataflow would still feed the NEW values. Fix: reload AFTER the
// bHi unpack. The definition order above is wrong; the launcher uses
// k_gemm8_fixed below.

__launch_bounds__(512, 2)
__global__ void k_gemm8_fixed(const unsigned short* __restrict__ A,
                              const int* __restrict__ Wq,
                              const float* __restrict__ SZ,
                              float* __restrict__ C) {
  __shared__ __attribute__((aligned(16))) unsigned char LDS[73792];

  const int tid = threadIdx.x;
  const int lane = tid & 63;
  const int w = tid >> 6;
  const int wm = w >> 2;
  const int wn = w & 3;
  const int u = lane & 15;
  const int h4 = lane >> 4;
  const int xor16 = (lane & 7) << 4;
  const int kpos0 = (h4 * 16) ^ xor16;
  const int kpos1 = (64 + h4 * 16) ^ xor16;
  const int aoff = u * 128;

  const int orig = blockIdx.x;
  const int xcd = orig & 7, loc = orig >> 3;
  const int qq = 21, rr = 4;
  const int swz = (xcd < rr) ? xcd * (qq + 1) + loc : rr * (qq + 1) + (xcd - rr) * qq + loc;
  const int m0 = (swz & 3) * 256;
  const int nb0 = (swz >> 2) * 256;

  const int kb_src = (((lane & 7) ^ ((lane >> 3) & 7)) << 4) >> 1;
  const int srow = w * 16 + (lane >> 3);
  const unsigned short* gA0 = A + (size_t)(m0 + srow) * K_DIM + kb_src;
  const unsigned short* gA1 = gA0 + (size_t)128 * K_DIM;
  const int ldsw = w * 2048;

  const int* gBw = Wq + (size_t)w * N_DIM + nb0 + lane * 4;
  const int n_base = nb0 + wn * 64 + u;
  const unsigned char* rdBw = LDS + BW_OFF + h4 * 1032 + (wn * 64 + u) * 4;

  f32x4 acc[8][4] = {};
  f32x2 sz[4];

  STAGE_A(gA0, 0, 0, 0);
  STAGE_A(gA1, 0, 0, 1);
  STAGE_BW(0);
  SBAR0();
#pragma unroll
  for (int nf = 0; nf < 4; ++nf)
    sz[nf] = *(const f32x2*)(SZ + ((size_t)(n_base + nf * 16)) * 2);  // g=0
  SBAR0();
  STAGE_A(gA0, 1, 32768, 0);
  asm volatile("s_waitcnt vmcnt(2)" ::: "memory");
  __builtin_amdgcn_s_barrier();

#pragma unroll 2
  for (int t = 0; t < NT; ++t) {
    const int cur = t & 1;
    const int bo_c = cur * 32768;
    const int bo_n = (cur ^ 1) * 32768;
    const unsigned char* rdA = LDS + bo_c + wm * REG_BYTES;

    bf16x8 aR[4][2], bF[4][2];
    int wrd[4][2];

    // phase 0
#pragma unroll
    for (int nf = 0; nf < 4; ++nf)
#pragma unroll
      for (int ks = 0; ks < 2; ++ks)
        wrd[nf][ks] = *(const int*)(rdBw + ks * 4128 + nf * 64);
#pragma unroll
    for (int mi = 0; mi < 4; ++mi) {
      aR[mi][0] = RD(rdA, mi * 2048 + aoff + kpos0);
      aR[mi][1] = RD(rdA, mi * 2048 + aoff + kpos1);
    }
    if (t + 1 < NT) STAGE_A(gA1, t + 1, bo_n, 1);
#pragma unroll
    for (int nf = 0; nf < 4; ++nf)     // unpack ALL 8 frags with tile-t's sz
#pragma unroll
      for (int ks = 0; ks < 2; ++ks) {
        int wv = wrd[nf][ks];
        float s = sz[nf][0], zz = sz[nf][1];
        bf16x8 f;
#pragma unroll
        for (int j = 0; j < 8; ++j)
          f[j] = (__bf16)fmaf((float)((wv >> (4 * j)) & 0xF), s, -zz);
        bF[nf][ks] = f;
      }
    __builtin_amdgcn_s_barrier();
    __builtin_amdgcn_s_setprio(1);
#pragma unroll
    for (int mi = 0; mi < 4; ++mi)
#pragma unroll
      for (int nf = 0; nf < 2; ++nf) {
        acc[mi][nf] = MFMA16(aR[mi][0], bF[nf][0], acc[mi][nf]);
        acc[mi][nf] = MFMA16(aR[mi][1], bF[nf][1], acc[mi][nf]);
      }
    __builtin_amdgcn_s_setprio(0);
    __builtin_amdgcn_s_barrier();

    // phase 1 (all B frags already unpacked; reload sz AFTER unpack, for t+1/t+2)
    if (t + 1 < NT) STAGE_BW(t + 1);
    SBAR0();
    if ((t & 1) && (t + 1 < NT)) {
      const int gg = (t + 1) >> 1;
#pragma unroll
      for (int nf = 0; nf < 4; ++nf)
        sz[nf] = *(const f32x2*)(SZ + ((size_t)gg * N_DIM + n_base + nf * 16) * 2);
    }
    SBAR0();
    __builtin_amdgcn_s_barrier();
    __builtin_amdgcn_s_setprio(1);
#pragma unroll
    for (int mi = 0; mi < 4; ++mi)
#pragma unroll
      for (int nf = 0; nf < 2; ++nf) {
        acc[mi][nf + 2] = MFMA16(aR[mi][0], bF[nf + 2][0], acc[mi][nf + 2]);
        acc[mi][nf + 2] = MFMA16(aR[mi][1], bF[nf + 2][1], acc[mi][nf + 2]);
      }
    __builtin_amdgcn_s_setprio(0);
    __builtin_amdgcn_s_barrier();

    // phase 2
#pragma unroll
    for (int mi = 0; mi < 4; ++mi) {
      aR[mi][0] = RD(rdA, (mi + 4) * 2048 + aoff + kpos0);
      aR[mi][1] = RD(rdA, (mi + 4) * 2048 + aoff + kpos1);
    }
    __builtin_amdgcn_s_barrier();
    __builtin_amdgcn_s_setprio(1);
#pragma unroll
    for (int mi = 0; mi < 4; ++mi)
#pragma unroll
      for (int nf = 0; nf < 2; ++nf) {
        acc[mi + 4][nf + 2] = MFMA16(aR[mi][0], bF[nf + 2][0], acc[mi + 4][nf + 2]);
        acc[mi + 4][nf + 2] = MFMA16(aR[mi][1], bF[nf + 2][1], acc[mi + 4][nf + 2]);
      }
    __builtin_amdgcn_s_setprio(0);
    __builtin_amdgcn_s_barrier();

    // phase 3
    if (t + 2 < NT) STAGE_A(gA0, t + 2, bo_c, 0);
    __builtin_amdgcn_s_barrier();
    __builtin_amdgcn_s_setprio(1);
#pragma unroll
    for (int mi = 0; mi < 4; ++mi)
#pragma unroll
      for (int nf = 0; nf < 2; ++nf) {
        acc[mi + 4][nf] = MFMA16(aR[mi][0], bF[nf][0], acc[mi + 4][nf]);
        acc[mi + 4][nf] = MFMA16(aR[mi][1], bF[nf][1], acc[mi + 4][nf]);
      }
    __builtin_amdgcn_s_setprio(0);
    if (t < NT - 2) {
      asm volatile("s_waitcnt vmcnt(2)" ::: "memory");
    } else {
      asm volatile("s_waitcnt vmcnt(0)" ::: "memory");
    }
    __builtin_amdgcn_s_barrier();
  }

  const int crow0 = m0 + wm * 128 + h4 * 4;
  const int ccol0 = nb0 + wn * 64 + u;
#pragma unroll
  for (int mi = 0; mi < 8; ++mi)
#pragma unroll
    for (int nf = 0; nf < 4; ++nf)
#pragma unroll
      for (int r = 0; r < 4; ++r)
        C[(size_t)(crow0 + mi * 16 + r) * N_DIM + ccol0 + nf * 16] = acc[mi][nf][r];
}

// ---------------- Fallback (ws too small) ----------------
__global__ void k_fallback(const float* __restrict__ x, const int* __restrict__ qw,
                           const float* __restrict__ scales, const int* __restrict__ qz,
                           float* __restrict__ C) {
  int t = blockIdx.x * 256 + threadIdx.x;
  int m = t / NC_DIM;
  int c = t % NC_DIM;
  float acc[8];
#pragma unroll
  for (int j = 0; j < 8; ++j) acc[j] = 0.f;
  for (int g = 0; g < G_DIM; ++g) {
    int zw = qz[(size_t)g * NC_DIM + c];
    float sj[8], zsj[8];
#pragma unroll
    for (int j = 0; j < 8; ++j) {
      sj[j] = scales[(size_t)g * N_DIM + c * 8 + j];
      zsj[j] = (float)((zw >> awq_shift(j)) & 0xF) * sj[j];
    }
    for (int k = g * GS; k < (g + 1) * GS; ++k) {
      float xv = x[(size_t)m * K_DIM + k];
      int wv = qw[(size_t)k * NC_DIM + c];
#pragma unroll
      for (int j = 0; j < 8; ++j) {
        float dq = fmaf((float)((wv >> awq_shift(j)) & 0xF), sj[j], -zsj[j]);
        acc[j] = fmaf(xv, dq, acc[j]);
      }
    }
  }
#pragma unroll
  for (int j = 0; j < 8; ++j)
    C[(size_t)m * N_DIM + c * 8 + j] = acc[j];
}

extern "C" void kernel_launch(void* const* d_in, const int* in_sizes, int n_in,
                              void* d_out, int out_size, void* d_ws, size_t ws_size,
                              hipStream_t stream) {
  (void)in_sizes; (void)n_in; (void)out_size;
  const float* x = (const float*)d_in[0];
  const int* qw = (const int*)d_in[1];
  const float* scales = (const float*)d_in[2];
  const int* qz = (const int*)d_in[3];
  float* C = (float*)d_out;

  const size_t xb_bytes = (size_t)M_DIM * K_DIM * 2;                 // 8 MB
  const size_t wq_bytes = (size_t)(K_DIM / 8) * N_DIM * 4;           // 22.5 MB
  const size_t sz_bytes = (size_t)G_DIM * N_DIM * 2 * 4;             // 2.8 MB

  if (ws_size >= xb_bytes + wq_bytes + sz_bytes) {
    unsigned short* xb = (unsigned short*)d_ws;
    int* Wq = (int*)((char*)d_ws + xb_bytes);
    float* SZ = (float*)((char*)d_ws + xb_bytes + wq_bytes);
    k_cvt_x<<<(M_DIM * K_DIM) / (256 * 8), 256, 0, stream>>>(x, xb);
    k_wqt<<<(K_DIM / 8) * NC_DIM / 256, 256, 0, stream>>>(qw, Wq);
    k_tab<<<G_DIM * N_DIM / 256, 256, 0, stream>>>(qz, scales, SZ);
    k_gemm8_fixed<<<(M_DIM / 256) * (N_DIM / 256), 512, 0, stream>>>(xb, Wq, SZ, C);
  } else {
    k_fallback<<<(M_DIM * NC_DIM) / 256, 256, 0, stream>>>(x, qw, scales, qz, C);
  }
}

// Round 5
// 135.021 us; speedup vs baseline: 1.3357x; 1.3357x over previous
//
#include <hip/hip_runtime.h>
#include <stdint.h>

// AWQGemm: x[1024,4096] f32, qweight[4096,1376] i32, scales[32,11008] f32,
// qzeros[32,1376] i32 -> C[1024,11008] f32
#define M_DIM 1024
#define K_DIM 4096
#define N_DIM 11008
#define NC_DIM 1376
#define G_DIM 32
#define GS 128

typedef __bf16 bf16x8 __attribute__((ext_vector_type(8)));
typedef float f32x4 __attribute__((ext_vector_type(4)));
typedef unsigned short ushort8 __attribute__((ext_vector_type(8)));

typedef __attribute__((address_space(1))) char as1_char;
typedef __attribute__((address_space(3))) char as3_char;
#define GLDS16(g, l) __builtin_amdgcn_global_load_lds((as1_char*)(g), (as3_char*)(l), 16, 0, 0)

static __device__ __forceinline__ int awq_shift(int j) {
  return ((j & 1) << 4) | ((j >> 1) << 2);
}

// fp32 -> bf16 bits, RNE
static __device__ __forceinline__ unsigned short f2bf(float f) {
  union { float f; uint32_t u; } c; c.f = f;
  uint32_t u = c.u;
  return (unsigned short)((u + 0x7FFFu + ((u >> 16) & 1u)) >> 16);
}

// ---------------- Stage 0: x fp32 -> bf16 ----------------
__global__ void k_cvt_x(const float* __restrict__ x, unsigned short* __restrict__ xb) {
  int i = blockIdx.x * blockDim.x + threadIdx.x;
  int base = i * 8;
  float4 v0 = *(const float4*)(x + base);
  float4 v1 = *(const float4*)(x + base + 4);
  ushort8 o;
  o[0] = f2bf(v0.x); o[1] = f2bf(v0.y); o[2] = f2bf(v0.z); o[3] = f2bf(v0.w);
  o[4] = f2bf(v1.x); o[5] = f2bf(v1.y); o[6] = f2bf(v1.z); o[7] = f2bf(v1.w);
  *(ushort8*)(xb + base) = o;
}

// ---------------- Stage 1: dequant W -> W^T bf16 [N][K] ----------------
__global__ void k_dequant(const int* __restrict__ qw, const float* __restrict__ scales,
                          const int* __restrict__ qz, unsigned short* __restrict__ wt) {
  __shared__ int wlds[64][17];
  const int t = threadIdx.x;
  const int k0 = blockIdx.x * 64;
  const int nb = blockIdx.y;
  const int n_glob0 = nb * 128;
  const int c0 = n_glob0 >> 3;
  const int g = k0 >> 7;
#pragma unroll
  for (int p = 0; p < 4; ++p) {
    int idx = p * 256 + t;
    int k = idx >> 4, c = idx & 15;
    wlds[k][c] = qw[(size_t)(k0 + k) * NC_DIM + c0 + c];
  }
  __syncthreads();
#pragma unroll
  for (int p = 0; p < 4; ++p) {
    int u = p * 256 + t;
    int k8 = u & 7;
    int nl = u >> 3;
    int j = nl & 7;
    int c = nl >> 3;
    int shift = awq_shift(j);
    float s = scales[(size_t)g * N_DIM + n_glob0 + nl];
    int zw = qz[(size_t)g * NC_DIM + c0 + c];
    float zs = (float)((zw >> shift) & 0xF) * s;
    ushort8 o;
#pragma unroll
    for (int i = 0; i < 8; ++i) {
      int wv = wlds[k8 * 8 + i][c];
      int nib = (wv >> shift) & 0xF;
      o[i] = f2bf(fmaf((float)nib, s, -zs));
    }
    *(ushort8*)(wt + (size_t)(nb * 128 + nl) * K_DIM + k0 + k8 * 8) = o;
  }
}

// ---------------- Stage 2: 256x256 8-phase bf16 GEMM ----------------
// R2 skeleton (proven 112.8us, 0 bank conflicts, race-free vmcnt FIFO).
// R5 deltas ONLY: (1) lgkmcnt(0)+sched_barrier(0) after pre-MFMA barriers
// (m201 wait discipline; rule #18 requires the sched_barrier), (2) bHi reads
// moved p1->p0 so p1/p3 are pure register-fed MFMA clusters. VGPR peak
// unchanged (aLo+bA+bB = 64 frag regs = R2's p2 peak).
#define BK 64
#define NT (K_DIM / 64)
#define REG_BYTES 16384

__device__ __forceinline__ void stage_half(const unsigned short* __restrict__ src, int row0, int T,
                                           unsigned char* lds_region, int w, int lane) {
  const int kb = (((lane & 7) ^ ((lane >> 3) & 7)) << 4);  // pre-swizzled source k-byte
  const int row = w * 16 + (lane >> 3);
  const unsigned short* g = src + (size_t)(row0 + row) * K_DIM + T * 64 + (kb >> 1);
  unsigned char* l = lds_region + w * 2048;  // wave-uniform; HW adds lane*16
  GLDS16(g, l);
  GLDS16(g + (size_t)8 * K_DIM, l + 1024);
}

#define RD(base, off) (*(const bf16x8*)((const unsigned char*)(base) + (off)))
#define MFMA16(a, b, c) __builtin_amdgcn_mfma_f32_16x16x32_bf16((a), (b), (c), 0, 0, 0)
#define LGKM0_PIN()                                        \
  do {                                                     \
    asm volatile("s_waitcnt lgkmcnt(0)" ::: "memory");     \
    __builtin_amdgcn_sched_barrier(0);                     \
  } while (0)

__launch_bounds__(512, 2)
__global__ void k_gemm8(const unsigned short* __restrict__ A,
                        const unsigned short* __restrict__ Bt,
                        float* __restrict__ C) {
  __shared__ __attribute__((aligned(16))) unsigned char LDS[131072];

  const int tid = threadIdx.x;
  const int lane = tid & 63;
  const int w = tid >> 6;       // 0..7
  const int wm = w >> 2;        // 0..1  (M half)
  const int wn = w & 3;         // 0..3  (N quarter)
  const int u = lane & 15;
  const int h = lane >> 4;      // 0..3
  const int xor16 = (lane & 7) << 4;
  const int kpos0 = (h * 16) ^ xor16;         // ks=0 swizzled k-byte
  const int kpos1 = (64 + h * 16) ^ xor16;    // ks=1
  const int aoff = u * 128;

  // bijective XCD swizzle: nwg=172 = 8*21+4
  const int orig = blockIdx.x;
  const int xcd = orig & 7, loc = orig >> 3;
  const int qq = 21, rr = 4;
  const int swz = (xcd < rr) ? xcd * (qq + 1) + loc : rr * (qq + 1) + (xcd - rr) * qq + loc;
  const int m0 = (swz & 3) * 256;    // M fastest: 4 row-tiles share a B panel per XCD chunk
  const int nb0 = (swz >> 2) * 256;

  f32x4 acc[8][4] = {};

  // ---- prologue: tile0 all 4 halves, then B0(1), A0(1); vmcnt(4); barrier
  stage_half(A,  m0,        0, LDS + 0 * REG_BYTES, w, lane);            // A0(0)
  stage_half(A,  m0 + 128,  0, LDS + 1 * REG_BYTES, w, lane);            // A1(0)
  stage_half(Bt, nb0,       0, LDS + 2 * REG_BYTES, w, lane);            // B0(0)
  stage_half(Bt, nb0 + 128, 0, LDS + 3 * REG_BYTES, w, lane);            // B1(0)
  stage_half(Bt, nb0,       1, LDS + 65536 + 2 * REG_BYTES, w, lane);    // B0(1)
  stage_half(A,  m0,        1, LDS + 65536 + 0 * REG_BYTES, w, lane);    // A0(1)
  asm volatile("s_waitcnt vmcnt(4)" ::: "memory");
  __builtin_amdgcn_s_barrier();

#pragma unroll 2
  for (int t = 0; t < NT; ++t) {
    const int cur = t & 1;
    unsigned char* bufc = LDS + cur * 65536;
    unsigned char* bufn = LDS + (cur ^ 1) * 65536;
    const unsigned char* rA = bufc + wm * REG_BYTES;
    const unsigned char* rB = bufc + (2 + (wn >> 1)) * REG_BYTES;
    const int bsub = (wn & 1) * 8192;

    bf16x8 aR[4][2], bLo[2][2], bHi[2][2];

    // ---------- phase 0: read bLo+bHi+A-lo (16 reads); stage A1(t+1) ----------
#pragma unroll
    for (int nf = 0; nf < 2; ++nf) {
      bLo[nf][0] = RD(rB, bsub + nf * 2048 + aoff + kpos0);
      bLo[nf][1] = RD(rB, bsub + nf * 2048 + aoff + kpos1);
      bHi[nf][0] = RD(rB, bsub + (nf + 2) * 2048 + aoff + kpos0);
      bHi[nf][1] = RD(rB, bsub + (nf + 2) * 2048 + aoff + kpos1);
    }
#pragma unroll
    for (int mi = 0; mi < 4; ++mi) {
      aR[mi][0] = RD(rA, mi * 2048 + aoff + kpos0);
      aR[mi][1] = RD(rA, mi * 2048 + aoff + kpos1);
    }
    if (t + 1 < NT) stage_half(A, m0 + 128, t + 1, bufn + 1 * REG_BYTES, w, lane);  // A1(t+1)
    __builtin_amdgcn_s_barrier();
    LGKM0_PIN();
    __builtin_amdgcn_s_setprio(1);
#pragma unroll
    for (int mi = 0; mi < 4; ++mi)
#pragma unroll
      for (int nf = 0; nf < 2; ++nf) {
        acc[mi][nf] = MFMA16(aR[mi][0], bLo[nf][0], acc[mi][nf]);
        acc[mi][nf] = MFMA16(aR[mi][1], bLo[nf][1], acc[mi][nf]);
      }
    __builtin_amdgcn_s_setprio(0);
    __builtin_amdgcn_s_barrier();

    // ---------- phase 1: no reads; stage B1(t+1); register-fed cluster ----------
    if (t + 1 < NT) stage_half(Bt, nb0 + 128, t + 1, bufn + 3 * REG_BYTES, w, lane);  // B1(t+1)
    __builtin_amdgcn_s_barrier();
    __builtin_amdgcn_s_setprio(1);
#pragma unroll
    for (int mi = 0; mi < 4; ++mi)
#pragma unroll
      for (int nf = 0; nf < 2; ++nf) {
        acc[mi][nf + 2] = MFMA16(aR[mi][0], bHi[nf][0], acc[mi][nf + 2]);
        acc[mi][nf + 2] = MFMA16(aR[mi][1], bHi[nf][1], acc[mi][nf + 2]);
      }
    __builtin_amdgcn_s_setprio(0);
    __builtin_amdgcn_s_barrier();

    // ---------- phase 2: read A-hi (8 reads); stage B0(t+2) ----------
#pragma unroll
    for (int mi = 0; mi < 4; ++mi) {
      aR[mi][0] = RD(rA, (mi + 4) * 2048 + aoff + kpos0);
      aR[mi][1] = RD(rA, (mi + 4) * 2048 + aoff + kpos1);
    }
    if (t + 2 < NT) stage_half(Bt, nb0, t + 2, bufc + 2 * REG_BYTES, w, lane);  // B0(t+2)
    __builtin_amdgcn_s_barrier();
    LGKM0_PIN();
    __builtin_amdgcn_s_setprio(1);
#pragma unroll
    for (int mi = 0; mi < 4; ++mi)
#pragma unroll
      for (int nf = 0; nf < 2; ++nf) {
        acc[mi + 4][nf + 2] = MFMA16(aR[mi][0], bHi[nf][0], acc[mi + 4][nf + 2]);
        acc[mi + 4][nf + 2] = MFMA16(aR[mi][1], bHi[nf][1], acc[mi + 4][nf + 2]);
      }
    __builtin_amdgcn_s_setprio(0);
    __builtin_amdgcn_s_barrier();

    // ---------- phase 3: no reads; stage A0(t+2); counted vmcnt ----------
    if (t + 2 < NT) stage_half(A, m0, t + 2, bufc + 0 * REG_BYTES, w, lane);  // A0(t+2)
    __builtin_amdgcn_s_barrier();
    __builtin_amdgcn_s_setprio(1);
#pragma unroll
    for (int mi = 0; mi < 4; ++mi)
#pragma unroll
      for (int nf = 0; nf < 2; ++nf) {
        acc[mi + 4][nf] = MFMA16(aR[mi][0], bLo[nf][0], acc[mi + 4][nf]);
        acc[mi + 4][nf] = MFMA16(aR[mi][1], bLo[nf][1], acc[mi + 4][nf]);
      }
    __builtin_amdgcn_s_setprio(0);
    if (t < NT - 2) {
      asm volatile("s_waitcnt vmcnt(4)" ::: "memory");
    } else {
      asm volatile("s_waitcnt vmcnt(0)" ::: "memory");
    }
    __builtin_amdgcn_s_barrier();
  }

  // ---- epilogue: C/D map col=lane&15, row=(lane>>4)*4+r [m89]
  const int crow0 = m0 + wm * 128 + h * 4;
  const int ccol0 = nb0 + wn * 64 + u;
#pragma unroll
  for (int mi = 0; mi < 8; ++mi)
#pragma unroll
    for (int nf = 0; nf < 4; ++nf)
#pragma unroll
      for (int r = 0; r < 4; ++r)
        C[(size_t)(crow0 + mi * 16 + r) * N_DIM + ccol0 + nf * 16] = acc[mi][nf][r];
}

// ---------------- Fallback (ws too small) ----------------
__global__ void k_fallback(const float* __restrict__ x, const int* __restrict__ qw,
                           const float* __restrict__ scales, const int* __restrict__ qz,
                           float* __restrict__ C) {
  int t = blockIdx.x * 256 + threadIdx.x;
  int m = t / NC_DIM;
  int c = t % NC_DIM;
  float acc[8];
#pragma unroll
  for (int j = 0; j < 8; ++j) acc[j] = 0.f;
  for (int g = 0; g < G_DIM; ++g) {
    int zw = qz[(size_t)g * NC_DIM + c];
    float sj[8], zsj[8];
#pragma unroll
    for (int j = 0; j < 8; ++j) {
      sj[j] = scales[(size_t)g * N_DIM + c * 8 + j];
      zsj[j] = (float)((zw >> awq_shift(j)) & 0xF) * sj[j];
    }
    for (int k = g * GS; k < (g + 1) * GS; ++k) {
      float xv = x[(size_t)m * K_DIM + k];
      int wv = qw[(size_t)k * NC_DIM + c];
#pragma unroll
      for (int j = 0; j < 8; ++j) {
        float dq = fmaf((float)((wv >> awq_shift(j)) & 0xF), sj[j], -zsj[j]);
        acc[j] = fmaf(xv, dq, acc[j]);
      }
    }
  }
#pragma unroll
  for (int j = 0; j < 8; ++j)
    C[(size_t)m * N_DIM + c * 8 + j] = acc[j];
}

extern "C" void kernel_launch(void* const* d_in, const int* in_sizes, int n_in,
                              void* d_out, int out_size, void* d_ws, size_t ws_size,
                              hipStream_t stream) {
  (void)in_sizes; (void)n_in; (void)out_size;
  const float* x = (const float*)d_in[0];
  const int* qw = (const int*)d_in[1];
  const float* scales = (const float*)d_in[2];
  const int* qz = (const int*)d_in[3];
  float* C = (float*)d_out;

  const size_t xb_bytes = (size_t)M_DIM * K_DIM * 2;
  const size_t wt_bytes = (size_t)N_DIM * K_DIM * 2;

  if (ws_size >= xb_bytes + wt_bytes) {
    unsigned short* xb = (unsigned short*)d_ws;
    unsigned short* wt = (unsigned short*)((char*)d_ws + xb_bytes);
    k_cvt_x<<<(M_DIM * K_DIM) / (256 * 8), 256, 0, stream>>>(x, xb);
    dim3 gd(K_DIM / 64, N_DIM / 128);
    k_dequant<<<gd, 256, 0, stream>>>(qw, scales, qz, wt);
    k_gemm8<<<(M_DIM / 256) * (N_DIM / 256), 512, 0, stream>>>(xb, wt, C);
  } else {
    k_fallback<<<(M_DIM * NC_DIM) / 256, 256, 0, stream>>>(x, qw, scales, qz, C);
  }
}

// Round 6
// 131.383 us; speedup vs baseline: 1.3727x; 1.0277x over previous
//
#include <hip/hip_runtime.h>
#include <stdint.h>

// AWQGemm: x[1024,4096] f32, qweight[4096,1376] i32, scales[32,11008] f32,
// qzeros[32,1376] i32 -> C[1024,11008] f32
//
// FINAL STRUCTURE (R2, best measured: 131.3 us total):
//   k_cvt_x   (~3 us):  x f32 -> bf16, short8-vectorized
//   k_dequant (~15 us): AWQ nibble-unpack -> W^T bf16 [N][K] via LDS transpose
//   k_gemm8  (~113 us): 256x256 8-phase counted-vmcnt bf16 GEMM (m201-class),
//                       global_load_lds w=16, XOR-swizzled LDS, XCD swizzle,
//                       setprio around MFMA clusters. 818 TF, 0 bank conflicts.
// Measured dead-ends: fused in-register dequant (+57us, lockstep VALU serializes),
// 32x32x16 MFMA (+7us, swizzle conflicts), lgkmcnt(0)-pin + read rebalance (+5us).
#define M_DIM 1024
#define K_DIM 4096
#define N_DIM 11008
#define NC_DIM 1376
#define G_DIM 32
#define GS 128

typedef __bf16 bf16x8 __attribute__((ext_vector_type(8)));
typedef float f32x4 __attribute__((ext_vector_type(4)));
typedef unsigned short ushort8 __attribute__((ext_vector_type(8)));

typedef __attribute__((address_space(1))) char as1_char;
typedef __attribute__((address_space(3))) char as3_char;
#define GLDS16(g, l) __builtin_amdgcn_global_load_lds((as1_char*)(g), (as3_char*)(l), 16, 0, 0)

static __device__ __forceinline__ int awq_shift(int j) {
  return ((j & 1) << 4) | ((j >> 1) << 2);
}

// fp32 -> bf16 bits, RNE
static __device__ __forceinline__ unsigned short f2bf(float f) {
  union { float f; uint32_t u; } c; c.f = f;
  uint32_t u = c.u;
  return (unsigned short)((u + 0x7FFFu + ((u >> 16) & 1u)) >> 16);
}

// ---------------- Stage 0: x fp32 -> bf16 ----------------
__global__ void k_cvt_x(const float* __restrict__ x, unsigned short* __restrict__ xb) {
  int i = blockIdx.x * blockDim.x + threadIdx.x;
  int base = i * 8;
  float4 v0 = *(const float4*)(x + base);
  float4 v1 = *(const float4*)(x + base + 4);
  ushort8 o;
  o[0] = f2bf(v0.x); o[1] = f2bf(v0.y); o[2] = f2bf(v0.z); o[3] = f2bf(v0.w);
  o[4] = f2bf(v1.x); o[5] = f2bf(v1.y); o[6] = f2bf(v1.z); o[7] = f2bf(v1.w);
  *(ushort8*)(xb + base) = o;
}

// ---------------- Stage 1: dequant W -> W^T bf16 [N][K] ----------------
__global__ void k_dequant(const int* __restrict__ qw, const float* __restrict__ scales,
                          const int* __restrict__ qz, unsigned short* __restrict__ wt) {
  __shared__ int wlds[64][17];
  const int t = threadIdx.x;
  const int k0 = blockIdx.x * 64;
  const int nb = blockIdx.y;
  const int n_glob0 = nb * 128;
  const int c0 = n_glob0 >> 3;
  const int g = k0 >> 7;
#pragma unroll
  for (int p = 0; p < 4; ++p) {
    int idx = p * 256 + t;
    int k = idx >> 4, c = idx & 15;
    wlds[k][c] = qw[(size_t)(k0 + k) * NC_DIM + c0 + c];
  }
  __syncthreads();
#pragma unroll
  for (int p = 0; p < 4; ++p) {
    int u = p * 256 + t;
    int k8 = u & 7;
    int nl = u >> 3;
    int j = nl & 7;
    int c = nl >> 3;
    int shift = awq_shift(j);
    float s = scales[(size_t)g * N_DIM + n_glob0 + nl];
    int zw = qz[(size_t)g * NC_DIM + c0 + c];
    float zs = (float)((zw >> shift) & 0xF) * s;
    ushort8 o;
#pragma unroll
    for (int i = 0; i < 8; ++i) {
      int wv = wlds[k8 * 8 + i][c];
      int nib = (wv >> shift) & 0xF;
      o[i] = f2bf(fmaf((float)nib, s, -zs));
    }
    *(ushort8*)(wt + (size_t)(nb * 128 + nl) * K_DIM + k0 + k8 * 8) = o;
  }
}

// ---------------- Stage 2: 256x256 8-phase bf16 GEMM ----------------
// C[M,N] = A[M,K] * Bt[N,K]^T.  8 waves (2M x 4N), BK=64, NT=64 K-tiles.
// LDS: 2 buffers x 4 regions (A0,A1,B0,B1; 128 rows x 128B, 16KB each).
// Per K-tile 4 phases:
//   p0: ds_read Alo(8)+Blo(4); stage A1(t+1); BAR; MFMA Q(Alo,Blo); BAR
//   p1: ds_read Bhi(4);        stage B1(t+1); BAR; MFMA Q(Alo,Bhi); BAR
//   p2: ds_read Ahi(8);        stage B0(t+2); BAR; MFMA Q(Ahi,Bhi); BAR
//   p3: (no reads);            stage A0(t+2); BAR; MFMA Q(Ahi,Blo); vmcnt; BAR
// Race analysis (region last-read phase -> overwrite-issue phase, barrier between):
//   A regions read p0,p2; overwritten (t+2) at p3 of same tile.     p2 < p3 OK
//   B regions read p0,p1; overwritten (t+2) at p2 of same tile.     p1 < p2 OK
//   buf^1 regions (tile t+1 stages at p0,p1) free since tile t-1.            OK
// vmcnt(4) at p3: tile t+1's last half staged at p1; 2 phases x 2 loads after
// -> <=4 outstanding guarantees all of t+1 landed before next tile's reads.
// Swizzle: kbyte ^= (row&7)<<4 applied on BOTH the pre-swizzled global source
// (linear LDS dest) and the ds_read address (rule #21).
#define BK 64
#define NT (K_DIM / BK)
#define REG_BYTES 16384

__device__ __forceinline__ void stage_half(const unsigned short* __restrict__ src, int row0, int T,
                                           unsigned char* lds_region, int w, int lane) {
  const int kb = (((lane & 7) ^ ((lane >> 3) & 7)) << 4);  // pre-swizzled source k-byte
  const int row = w * 16 + (lane >> 3);
  const unsigned short* g = src + (size_t)(row0 + row) * K_DIM + T * 64 + (kb >> 1);
  unsigned char* l = lds_region + w * 2048;  // wave-uniform; HW adds lane*16
  GLDS16(g, l);
  GLDS16(g + (size_t)8 * K_DIM, l + 1024);
}

#define RD(base, off) (*(const bf16x8*)((const unsigned char*)(base) + (off)))
#define MFMA16(a, b, c) __builtin_amdgcn_mfma_f32_16x16x32_bf16((a), (b), (c), 0, 0, 0)

__launch_bounds__(512, 2)
__global__ void k_gemm8(const unsigned short* __restrict__ A,
                        const unsigned short* __restrict__ Bt,
                        float* __restrict__ C) {
  __shared__ __attribute__((aligned(16))) unsigned char LDS[131072];

  const int tid = threadIdx.x;
  const int lane = tid & 63;
  const int w = tid >> 6;       // 0..7
  const int wm = w >> 2;        // 0..1  (M half)
  const int wn = w & 3;         // 0..3  (N quarter)
  const int u = lane & 15;
  const int h = lane >> 4;      // 0..3
  const int xor16 = (lane & 7) << 4;
  const int kpos0 = (h * 16) ^ xor16;         // ks=0 swizzled k-byte
  const int kpos1 = (64 + h * 16) ^ xor16;    // ks=1
  const int aoff = u * 128;

  // bijective XCD swizzle: nwg=172 = 8*21+4
  const int orig = blockIdx.x;
  const int xcd = orig & 7, loc = orig >> 3;
  const int qq = 21, rr = 4;
  const int swz = (xcd < rr) ? xcd * (qq + 1) + loc : rr * (qq + 1) + (xcd - rr) * qq + loc;
  const int m0 = (swz & 3) * 256;    // M fastest: 4 row-tiles share a B panel per XCD chunk
  const int nb0 = (swz >> 2) * 256;

  f32x4 acc[8][4] = {};

  // ---- prologue: tile0 all 4 halves, then B0(1), A0(1); vmcnt(4); barrier
  stage_half(A,  m0,        0, LDS + 0 * REG_BYTES, w, lane);            // A0(0)
  stage_half(A,  m0 + 128,  0, LDS + 1 * REG_BYTES, w, lane);            // A1(0)
  stage_half(Bt, nb0,       0, LDS + 2 * REG_BYTES, w, lane);            // B0(0)
  stage_half(Bt, nb0 + 128, 0, LDS + 3 * REG_BYTES, w, lane);            // B1(0)
  stage_half(Bt, nb0,       1, LDS + 65536 + 2 * REG_BYTES, w, lane);    // B0(1)
  stage_half(A,  m0,        1, LDS + 65536 + 0 * REG_BYTES, w, lane);    // A0(1)
  asm volatile("s_waitcnt vmcnt(4)" ::: "memory");
  __builtin_amdgcn_s_barrier();

#pragma unroll 2
  for (int t = 0; t < NT; ++t) {
    const int cur = t & 1;
    unsigned char* bufc = LDS + cur * 65536;
    unsigned char* bufn = LDS + (cur ^ 1) * 65536;
    const unsigned char* rA = bufc + wm * REG_BYTES;
    const unsigned char* rB = bufc + (2 + (wn >> 1)) * REG_BYTES;
    const int bsub = (wn & 1) * 8192;

    bf16x8 aR[4][2], bLo[2][2], bHi[2][2];

    // ---------- phase 0 ----------
#pragma unroll
    for (int mi = 0; mi < 4; ++mi) {
      aR[mi][0] = RD(rA, mi * 2048 + aoff + kpos0);
      aR[mi][1] = RD(rA, mi * 2048 + aoff + kpos1);
    }
#pragma unroll
    for (int nf = 0; nf < 2; ++nf) {
      bLo[nf][0] = RD(rB, bsub + nf * 2048 + aoff + kpos0);
      bLo[nf][1] = RD(rB, bsub + nf * 2048 + aoff + kpos1);
    }
    if (t + 1 < NT) stage_half(A, m0 + 128, t + 1, bufn + 1 * REG_BYTES, w, lane);  // A1(t+1)
    __builtin_amdgcn_s_barrier();
    __builtin_amdgcn_s_setprio(1);
#pragma unroll
    for (int mi = 0; mi < 4; ++mi)
#pragma unroll
      for (int nf = 0; nf < 2; ++nf) {
        acc[mi][nf] = MFMA16(aR[mi][0], bLo[nf][0], acc[mi][nf]);
        acc[mi][nf] = MFMA16(aR[mi][1], bLo[nf][1], acc[mi][nf]);
      }
    __builtin_amdgcn_s_setprio(0);
    __builtin_amdgcn_s_barrier();

    // ---------- phase 1 ----------
#pragma unroll
    for (int nf = 0; nf < 2; ++nf) {
      bHi[nf][0] = RD(rB, bsub + (nf + 2) * 2048 + aoff + kpos0);
      bHi[nf][1] = RD(rB, bsub + (nf + 2) * 2048 + aoff + kpos1);
    }
    if (t + 1 < NT) stage_half(Bt, nb0 + 128, t + 1, bufn + 3 * REG_BYTES, w, lane);  // B1(t+1)
    __builtin_amdgcn_s_barrier();
    __builtin_amdgcn_s_setprio(1);
#pragma unroll
    for (int mi = 0; mi < 4; ++mi)
#pragma unroll
      for (int nf = 0; nf < 2; ++nf) {
        acc[mi][nf + 2] = MFMA16(aR[mi][0], bHi[nf][0], acc[mi][nf + 2]);
        acc[mi][nf + 2] = MFMA16(aR[mi][1], bHi[nf][1], acc[mi][nf + 2]);
      }
    __builtin_amdgcn_s_setprio(0);
    __builtin_amdgcn_s_barrier();

    // ---------- phase 2 ----------
#pragma unroll
    for (int mi = 0; mi < 4; ++mi) {
      aR[mi][0] = RD(rA, (mi + 4) * 2048 + aoff + kpos0);
      aR[mi][1] = RD(rA, (mi + 4) * 2048 + aoff + kpos1);
    }
    if (t + 2 < NT) stage_half(Bt, nb0, t + 2, bufc + 2 * REG_BYTES, w, lane);  // B0(t+2)
    __builtin_amdgcn_s_barrier();
    __builtin_amdgcn_s_setprio(1);
#pragma unroll
    for (int mi = 0; mi < 4; ++mi)
#pragma unroll
      for (int nf = 0; nf < 2; ++nf) {
        acc[mi + 4][nf + 2] = MFMA16(aR[mi][0], bHi[nf][0], acc[mi + 4][nf + 2]);
        acc[mi + 4][nf + 2] = MFMA16(aR[mi][1], bHi[nf][1], acc[mi + 4][nf + 2]);
      }
    __builtin_amdgcn_s_setprio(0);
    __builtin_amdgcn_s_barrier();

    // ---------- phase 3 ----------
    if (t + 2 < NT) stage_half(A, m0, t + 2, bufc + 0 * REG_BYTES, w, lane);  // A0(t+2)
    __builtin_amdgcn_s_barrier();
    __builtin_amdgcn_s_setprio(1);
#pragma unroll
    for (int mi = 0; mi < 4; ++mi)
#pragma unroll
      for (int nf = 0; nf < 2; ++nf) {
        acc[mi + 4][nf] = MFMA16(aR[mi][0], bLo[nf][0], acc[mi + 4][nf]);
        acc[mi + 4][nf] = MFMA16(aR[mi][1], bLo[nf][1], acc[mi + 4][nf]);
      }
    __builtin_amdgcn_s_setprio(0);
    if (t < NT - 2) {
      asm volatile("s_waitcnt vmcnt(4)" ::: "memory");
    } else {
      asm volatile("s_waitcnt vmcnt(0)" ::: "memory");
    }
    __builtin_amdgcn_s_barrier();
  }

  // ---- epilogue: C/D map col=lane&15, row=(lane>>4)*4+r [m89]
  const int crow0 = m0 + wm * 128 + h * 4;
  const int ccol0 = nb0 + wn * 64 + u;
#pragma unroll
  for (int mi = 0; mi < 8; ++mi)
#pragma unroll
    for (int nf = 0; nf < 4; ++nf)
#pragma unroll
      for (int r = 0; r < 4; ++r)
        C[(size_t)(crow0 + mi * 16 + r) * N_DIM + ccol0 + nf * 16] = acc[mi][nf][r];
}

// ---------------- Fallback (ws too small) ----------------
__global__ void k_fallback(const float* __restrict__ x, const int* __restrict__ qw,
                           const float* __restrict__ scales, const int* __restrict__ qz,
                           float* __restrict__ C) {
  int t = blockIdx.x * 256 + threadIdx.x;
  int m = t / NC_DIM;
  int c = t % NC_DIM;
  float acc[8];
#pragma unroll
  for (int j = 0; j < 8; ++j) acc[j] = 0.f;
  for (int g = 0; g < G_DIM; ++g) {
    int zw = qz[(size_t)g * NC_DIM + c];
    float sj[8], zsj[8];
#pragma unroll
    for (int j = 0; j < 8; ++j) {
      sj[j] = scales[(size_t)g * N_DIM + c * 8 + j];
      zsj[j] = (float)((zw >> awq_shift(j)) & 0xF) * sj[j];
    }
    for (int k = g * GS; k < (g + 1) * GS; ++k) {
      float xv = x[(size_t)m * K_DIM + k];
      int wv = qw[(size_t)k * NC_DIM + c];
#pragma unroll
      for (int j = 0; j < 8; ++j) {
        float dq = fmaf((float)((wv >> awq_shift(j)) & 0xF), sj[j], -zsj[j]);
        acc[j] = fmaf(xv, dq, acc[j]);
      }
    }
  }
#pragma unroll
  for (int j = 0; j < 8; ++j)
    C[(size_t)m * N_DIM + c * 8 + j] = acc[j];
}

extern "C" void kernel_launch(void* const* d_in, const int* in_sizes, int n_in,
                              void* d_out, int out_size, void* d_ws, size_t ws_size,
                              hipStream_t stream) {
  (void)in_sizes; (void)n_in; (void)out_size;
  const float* x = (const float*)d_in[0];
  const int* qw = (const int*)d_in[1];
  const float* scales = (const float*)d_in[2];
  const int* qz = (const int*)d_in[3];
  float* C = (float*)d_out;

  const size_t xb_bytes = (size_t)M_DIM * K_DIM * 2;
  const size_t wt_bytes = (size_t)N_DIM * K_DIM * 2;

  if (ws_size >= xb_bytes + wt_bytes) {
    unsigned short* xb = (unsigned short*)d_ws;
    unsigned short* wt = (unsigned short*)((char*)d_ws + xb_bytes);
    k_cvt_x<<<(M_DIM * K_DIM) / (256 * 8), 256, 0, stream>>>(x, xb);
    dim3 gd(K_DIM / 64, N_DIM / 128);
    k_dequant<<<gd, 256, 0, stream>>>(qw, scales, qz, wt);
    k_gemm8<<<(M_DIM / 256) * (N_DIM / 256), 512, 0, stream>>>(xb, wt, C);
  } else {
    k_fallback<<<(M_DIM * NC_DIM) / 256, 256, 0, stream>>>(x, qw, scales, qz, C);
  }
}